// Round 10
// baseline (124.462 us; speedup 1.0000x reference)
//
#include <hip/hip_runtime.h>
#include <math.h>
#include <stdint.h>

#define NJ 14
#define NE 42                 // floats per item per tensor
#define WPB 2                 // waves per block
#define TPB (64 * WPB)
#define IPW 128               // items per WAVE (2 per lane, interleaved)
#define TEN_DW (IPW * NE)     // 5376 dw per tensor per wave = 21 x dma16 EXACTLY
#define WAVE_LDS_DW (2 * TEN_DW)  // pred+gt: 10752 dw = 43008 B per wave
#define SWEEPS 3              // verified bit-exact vs reference (R6 absmax 0.0)

__device__ __forceinline__ float frcp(float x) { return __builtin_amdgcn_rcpf(x); }
__device__ __forceinline__ float frsq(float x) { return __builtin_amdgcn_rsqf(x); }
__device__ __forceinline__ float fsqr(float x) { return __builtin_amdgcn_sqrtf(x); }

typedef uint32_t u32_as1 __attribute__((address_space(1)));
typedef uint32_t u32_as3 __attribute__((address_space(3)));

__device__ __forceinline__ void dma16(const float* g, const float* l) {
    __builtin_amdgcn_global_load_lds((const u32_as1*)(uintptr_t)g,
                                     (u32_as3*)(uintptr_t)l, 16, 0, 0);
}

// Branchless cyclic Jacobi rotation on symmetric A, accumulating V.
template <int p, int q, int r>
__device__ __forceinline__ void jrot(float (&A)[3][3], float (&V)[3][3]) {
    float apq = A[p][q];
    float apq_s = apq + copysignf(1e-30f, apq);
    float tau = (A[q][q] - A[p][p]) * 0.5f * frcp(apq_s);
    float t = copysignf(frcp(fabsf(tau) + fsqr(1.0f + tau * tau)), tau);
    float c = frsq(1.0f + t * t);
    float s = t * c;
    float app = A[p][p], aqq = A[q][q];
    A[p][p] = app - t * apq;
    A[q][q] = aqq + t * apq;
    A[p][q] = 0.0f;
    A[q][p] = 0.0f;
    float arp = A[r][p], arq = A[r][q];
    A[r][p] = c * arp - s * arq;
    A[p][r] = A[r][p];
    A[r][q] = s * arp + c * arq;
    A[q][r] = A[r][q];
#pragma unroll
    for (int k = 0; k < 3; ++k) {
        float vkp = V[k][p], vkq = V[k][q];
        V[k][p] = c * vkp - s * vkq;
        V[k][q] = s * vkp + c * vkq;
    }
}

// R10 rationale (ledger: R2 HBM-trips, R3 spill, R4 occupancy, R6 chain length,
// R7 ILP-with-scattered-loads, R8 wg-granularity, R9 per-wave pipelining — all
// falsified; wall pinned at ~42 us with per-CU slice-span overlap stuck at ~1.8).
// This round: halve the spans per CU (8 instead of 16) by giving each wave TWO
// items per lane, with BOTH tensors DMA->LDS (removing R7's scatter confound)
// and the two dependency chains interleaved. Staging: 128 items x 42 dw = 5376
// dw = exactly 21 dma16 per tensor — no tail op, no pad, no clamp on full slices.
__global__ __launch_bounds__(TPB) void pampjpe_kernel(
    const float* __restrict__ pred, const float* __restrict__ gt,
    float* __restrict__ out, int n_items) {
    __shared__ float s[WPB * WAVE_LDS_DW];  // 86016 B

    const int tid = threadIdx.x;
    const int w = tid >> 6;
    const int lane = tid & 63;
    const int task = blockIdx.x * WPB + w;   // wave-task id (2048 total)
    const int blk = task * TEN_DW;           // dword base; fits int32
    const int totdw = n_items * NE;
    const int lim4 = totdw - 4;
    float* sw = s + w * WAVE_LDS_DW;

    // ---- stage both tensors, 42 dma16 ops, one latency ----
    if (blk + TEN_DW <= totdw) {
#pragma unroll
        for (int k = 0; k < 21; ++k)
            dma16(pred + blk + k * 256 + lane * 4, sw + k * 256);
#pragma unroll
        for (int k = 0; k < 21; ++k)
            dma16(gt + blk + k * 256 + lane * 4, sw + TEN_DW + k * 256);
    } else {
#pragma unroll
        for (int k = 0; k < 21; ++k) {
            int g = blk + k * 256 + lane * 4;
            g = g > lim4 ? lim4 : g;
            dma16(pred + g, sw + k * 256);
        }
#pragma unroll
        for (int k = 0; k < 21; ++k) {
            int g = blk + k * 256 + lane * 4;
            g = g > lim4 ? lim4 : g;
            dma16(gt + g, sw + TEN_DW + k * 256);
        }
    }
    __builtin_amdgcn_s_waitcnt(0x0F70);  // vmcnt(0)
    __builtin_amdgcn_sched_barrier(0);

    // Two items per lane: lane and lane+64 within the wave's 128-item slice.
    const float* sp[2] = {sw + lane * NE, sw + (lane + 64) * NE};
    const float* sg[2] = {sw + TEN_DW + lane * NE, sw + TEN_DW + (lane + 64) * NE};

    // ---- pass 1: moments, chains interleaved ----
    float Sp[2][3], Sg[2][3], pp[2], M[2][3][3];
#pragma unroll
    for (int u = 0; u < 2; ++u) {
        Sp[u][0] = Sp[u][1] = Sp[u][2] = 0.f;
        Sg[u][0] = Sg[u][1] = Sg[u][2] = 0.f;
        pp[u] = 0.f;
#pragma unroll
        for (int i = 0; i < 3; ++i)
#pragma unroll
            for (int j = 0; j < 3; ++j) M[u][i][j] = 0.f;
    }
#pragma unroll
    for (int j = 0; j < NJ; ++j) {
#pragma unroll
        for (int u = 0; u < 2; ++u) {
            float px = sp[u][3 * j + 0], py = sp[u][3 * j + 1], pz = sp[u][3 * j + 2];
            float gx = sg[u][3 * j + 0], gy = sg[u][3 * j + 1], gz = sg[u][3 * j + 2];
            Sp[u][0] += px; Sp[u][1] += py; Sp[u][2] += pz;
            Sg[u][0] += gx; Sg[u][1] += gy; Sg[u][2] += gz;
            pp[u] += px * px + py * py + pz * pz;
            M[u][0][0] += px * gx; M[u][0][1] += px * gy; M[u][0][2] += px * gz;
            M[u][1][0] += py * gx; M[u][1][1] += py * gy; M[u][1][2] += py * gz;
            M[u][2][0] += pz * gx; M[u][2][1] += pz * gy; M[u][2][2] += pz * gz;
        }
    }
    // Anti-spill fence (round-2 lesson): pass-1 LDS reads die here; pass 2
    // re-streams from LDS instead of keeping 168 floats live across Jacobi.
    __asm__ __volatile__("" ::: "memory");

    const float invJ = 1.0f / (float)NJ;
    float mp[2][3], mg[2][3], sR[2][3][3];
    float K[2][3][3], A[2][3][3], V[2][3][3], var1[2];
#pragma unroll
    for (int u = 0; u < 2; ++u) {
#pragma unroll
        for (int d = 0; d < 3; ++d) {
            mp[u][d] = Sp[u][d] * invJ;
            mg[u][d] = Sg[u][d] * invJ;
        }
#pragma unroll
        for (int i = 0; i < 3; ++i)
#pragma unroll
            for (int j = 0; j < 3; ++j)
                K[u][i][j] = M[u][i][j] - (float)NJ * mp[u][i] * mg[u][j];
        var1[u] = pp[u] - (float)NJ * (mp[u][0] * mp[u][0] + mp[u][1] * mp[u][1] +
                                       mp[u][2] * mp[u][2]);
        var1[u] = fmaxf(var1[u], 1e-30f);
#pragma unroll
        for (int i = 0; i < 3; ++i)
#pragma unroll
            for (int j = 0; j < 3; ++j)
                A[u][i][j] = K[u][0][i] * K[u][0][j] + K[u][1][i] * K[u][1][j] +
                             K[u][2][i] * K[u][2][j];
        V[u][0][0] = 1.f; V[u][0][1] = 0.f; V[u][0][2] = 0.f;
        V[u][1][0] = 0.f; V[u][1][1] = 1.f; V[u][1][2] = 0.f;
        V[u][2][0] = 0.f; V[u][2][1] = 0.f; V[u][2][2] = 1.f;
    }
    // Interleaved Jacobi: both items' rotations in each step fill each
    // other's transcendental-latency stalls (this was R7's sound core).
#pragma unroll
    for (int sweep = 0; sweep < SWEEPS; ++sweep) {
#pragma unroll
        for (int u = 0; u < 2; ++u) jrot<0, 1, 2>(A[u], V[u]);
#pragma unroll
        for (int u = 0; u < 2; ++u) jrot<0, 2, 1>(A[u], V[u]);
#pragma unroll
        for (int u = 0; u < 2; ++u) jrot<1, 2, 0>(A[u], V[u]);
    }

#pragma unroll
    for (int u = 0; u < 2; ++u) {
        float(&Au)[3][3] = A[u];
        float(&Vu)[3][3] = V[u];
        float(&Ku)[3][3] = K[u];
        float lam0 = Au[0][0], lam1 = Au[1][1], lam2 = Au[2][2];
#define SWAPCOL(la, lb, a, b)                                         \
    {                                                                 \
        float _t;                                                     \
        _t = la; la = lb; lb = _t;                                    \
        _t = Vu[0][a]; Vu[0][a] = Vu[0][b]; Vu[0][b] = _t;            \
        _t = Vu[1][a]; Vu[1][a] = Vu[1][b]; Vu[1][b] = _t;            \
        _t = Vu[2][a]; Vu[2][a] = Vu[2][b]; Vu[2][b] = _t;            \
    }
        if (lam0 < lam1) SWAPCOL(lam0, lam1, 0, 1)
        if (lam0 < lam2) SWAPCOL(lam0, lam2, 0, 2)
        if (lam1 < lam2) SWAPCOL(lam1, lam2, 1, 2)
#undef SWAPCOL

        float v0[3] = {Vu[0][0], Vu[1][0], Vu[2][0]};
        float v1[3] = {Vu[0][1], Vu[1][1], Vu[2][1]};
        float v2[3] = {Vu[0][2], Vu[1][2], Vu[2][2]};

        // det(V) = +1
        float cxx = v0[1] * v1[2] - v0[2] * v1[1];
        float cxy = v0[2] * v1[0] - v0[0] * v1[2];
        float cxz = v0[0] * v1[1] - v0[1] * v1[0];
        float detv = cxx * v2[0] + cxy * v2[1] + cxz * v2[2];
        if (detv < 0.f) { v2[0] = -v2[0]; v2[1] = -v2[1]; v2[2] = -v2[2]; }

        // U via K*v + Gram-Schmidt; u3 = u1 x u2 -> det(U)=+1
        float w0[3], w1[3];
#pragma unroll
        for (int i = 0; i < 3; ++i) {
            w0[i] = Ku[i][0] * v0[0] + Ku[i][1] * v0[1] + Ku[i][2] * v0[2];
            w1[i] = Ku[i][0] * v1[0] + Ku[i][1] * v1[1] + Ku[i][2] * v1[2];
        }
        float inv0 =
            frsq(fmaxf(w0[0] * w0[0] + w0[1] * w0[1] + w0[2] * w0[2], 1e-30f));
        float u1[3] = {w0[0] * inv0, w0[1] * inv0, w0[2] * inv0};
        float d1 = u1[0] * w1[0] + u1[1] * w1[1] + u1[2] * w1[2];
        w1[0] -= d1 * u1[0]; w1[1] -= d1 * u1[1]; w1[2] -= d1 * u1[2];
        float inv1 =
            frsq(fmaxf(w1[0] * w1[0] + w1[1] * w1[1] + w1[2] * w1[2], 1e-30f));
        float u2[3] = {w1[0] * inv1, w1[1] * inv1, w1[2] * inv1};
        float u3[3] = {u1[1] * u2[2] - u1[2] * u2[1],
                       u1[2] * u2[0] - u1[0] * u2[2],
                       u1[0] * u2[1] - u1[1] * u2[0]};

        // R = V U^T; fold scale in
        float R[3][3];
#pragma unroll
        for (int i = 0; i < 3; ++i) {
            R[i][0] = v0[i] * u1[0] + v1[i] * u2[0] + v2[i] * u3[0];
            R[i][1] = v0[i] * u1[1] + v1[i] * u2[1] + v2[i] * u3[1];
            R[i][2] = v0[i] * u1[2] + v1[i] * u2[2] + v2[i] * u3[2];
        }
        float trRK = 0.f;
#pragma unroll
        for (int i = 0; i < 3; ++i)
#pragma unroll
            for (int j = 0; j < 3; ++j)
                trRK += R[i][j] * Ku[j][i];
        float scale = trRK * frcp(var1[u]);
#pragma unroll
        for (int i = 0; i < 3; ++i)
#pragma unroll
            for (int j = 0; j < 3; ++j)
                sR[u][i][j] = scale * R[i][j];
    }

    // ---- pass 2: loss, both tensors re-streamed from LDS, interleaved ----
    float acc[2] = {0.f, 0.f};
#pragma unroll
    for (int j = 0; j < NJ; ++j) {
#pragma unroll
        for (int u = 0; u < 2; ++u) {
            float x0 = sp[u][3 * j + 0] - mp[u][0];
            float x1 = sp[u][3 * j + 1] - mp[u][1];
            float x2 = sp[u][3 * j + 2] - mp[u][2];
            float y0 = sg[u][3 * j + 0] - mg[u][0];
            float y1 = sg[u][3 * j + 1] - mg[u][1];
            float y2 = sg[u][3 * j + 2] - mg[u][2];
            float e0 = sR[u][0][0] * x0 + sR[u][0][1] * x1 + sR[u][0][2] * x2 - y0;
            float e1 = sR[u][1][0] * x0 + sR[u][1][1] * x1 + sR[u][1][2] * x2 - y1;
            float e2 = sR[u][2][0] * x0 + sR[u][2][1] * x1 + sR[u][2][2] * x2 - y2;
            acc[u] += fsqr(e0 * e0 + e1 * e1 + e2 * e2);
        }
    }
    const int me = task * IPW + lane;
    if (me < n_items) out[me] = acc[0] * invJ;
    if (me + 64 < n_items) out[me + 64] = acc[1] * invJ;
}

extern "C" void kernel_launch(void* const* d_in, const int* in_sizes, int n_in,
                              void* d_out, int out_size, void* d_ws, size_t ws_size,
                              hipStream_t stream) {
    const float* pred = (const float*)d_in[0];
    const float* gt = (const float*)d_in[1];
    float* out = (float*)d_out;
    int n_items = in_sizes[0] / NE;                    // 262144
    int per_blk = WPB * IPW;                           // 256 items per block
    int grid = (n_items + per_blk - 1) / per_blk;      // 1024
    pampjpe_kernel<<<grid, TPB, 0, stream>>>(pred, gt, out, n_items);
}

// Round 11
// 108.199 us; speedup vs baseline: 1.1503x; 1.1503x over previous
//
#include <hip/hip_runtime.h>
#include <math.h>
#include <stdint.h>

#define NJ 14
#define NE 42                // floats per item per tensor
#define TPB 64               // ONE wave per block -> wave-synchronous, zero barriers
#define SLICE_DW (TPB * NE)  // 2688 dwords = 10752 B per tensor
#define BUF_DW (2 * SLICE_DW)  // pred + gt resident together: 21504 B

// FINAL-FORM RATIONALE (rounds 1-10 ledger): wall is pinned at ~41-42 us by the
// L3(Infinity-Cache)->CU read path: inputs (88 MB) are L3-resident in steady
// state (R10: FETCH 1 MB, hbm 14 GB/s) and every well-formed variant sustains
// ~2.1 TB/s of input reads regardless of occupancy (1.8-4.8 waves/CU), wg
// shape, pipelining depth, ILP, or chain length. 88 MB / 2.1 TB/s = 42 us.
// Falsified along the way: HBM double-trips (R2), scratch spill (R2->R3),
// LDS-occupancy cap (R4), Jacobi chain length (R6), wg granularity (R8),
// per-wave pipelining (R9), items-per-lane ILP (R7, R10). This kernel is the
// traffic-minimal, best-benched structure (106.7 us): each tensor read exactly
// once from L3 via coalesced DMA; gt pass-2 re-read is an L2 hit.
__device__ __forceinline__ float frcp(float x) { return __builtin_amdgcn_rcpf(x); }
__device__ __forceinline__ float frsq(float x) { return __builtin_amdgcn_rsqf(x); }
__device__ __forceinline__ float fsqr(float x) { return __builtin_amdgcn_sqrtf(x); }

typedef uint32_t u32_as1 __attribute__((address_space(1)));
typedef uint32_t u32_as3 __attribute__((address_space(3)));

__device__ __forceinline__ void dma16(const float* g, const float* l) {
    __builtin_amdgcn_global_load_lds((const u32_as1*)(uintptr_t)g,
                                     (u32_as3*)(uintptr_t)l, 16, 0, 0);
}
__device__ __forceinline__ void dma4(const float* g, const float* l) {
    __builtin_amdgcn_global_load_lds((const u32_as1*)(uintptr_t)g,
                                     (u32_as3*)(uintptr_t)l, 4, 0, 0);
}

// Stage one tensor's 2688-dword slice: 10x dma16 + 2x dma4 tail = 12 VMEM ops.
__device__ __forceinline__ void stage_tensor(const float* __restrict__ g,
                                             const float* sbase, long long gbase,
                                             long long lim4, long long lim1,
                                             int tid) {
#pragma unroll
    for (int k = 0; k < 10; ++k) {
        long long idx = gbase + k * (TPB * 4) + (long long)tid * 4;
        idx = idx > lim4 ? lim4 : idx;  // OOB lanes clamp; their items unused
        dma16(g + idx, sbase + k * (TPB * 4));
    }
#pragma unroll
    for (int t = 0; t < 2; ++t) {
        long long idx = gbase + 10 * (TPB * 4) + t * TPB + tid;
        idx = idx > lim1 ? lim1 : idx;
        dma4(g + idx, sbase + 10 * (TPB * 4) + t * TPB);
    }
}

// Branchless cyclic Jacobi rotation on symmetric A, accumulating V.
template <int p, int q, int r>
__device__ __forceinline__ void jrot(float A[3][3], float V[3][3]) {
    float apq = A[p][q];
    float apq_s = apq + copysignf(1e-30f, apq);
    float tau = (A[q][q] - A[p][p]) * 0.5f * frcp(apq_s);
    float t = copysignf(frcp(fabsf(tau) + fsqr(1.0f + tau * tau)), tau);
    float c = frsq(1.0f + t * t);
    float s = t * c;
    float app = A[p][p], aqq = A[q][q];
    A[p][p] = app - t * apq;
    A[q][q] = aqq + t * apq;
    A[p][q] = 0.0f;
    A[q][p] = 0.0f;
    float arp = A[r][p], arq = A[r][q];
    A[r][p] = c * arp - s * arq;
    A[p][r] = A[r][p];
    A[r][q] = s * arp + c * arq;
    A[q][r] = A[r][q];
#pragma unroll
    for (int k = 0; k < 3; ++k) {
        float vkp = V[k][p], vkq = V[k][q];
        V[k][p] = c * vkp - s * vkq;
        V[k][q] = s * vkp + c * vkq;
    }
}

__global__ __launch_bounds__(TPB) void pampjpe_kernel(
    const float* __restrict__ pred, const float* __restrict__ gt,
    float* __restrict__ out, int n_items) {
    __shared__ float s[BUF_DW];

    const int tid = threadIdx.x;  // lane id (wave64)
    const int me = blockIdx.x * TPB + tid;
    const long long blk_base = (long long)blockIdx.x * SLICE_DW;  // dword index
    const long long total = (long long)n_items * NE;
    const long long lim4 = total - 4;
    const long long lim1 = total - 1;

    // ---- one 24-DMA burst: both tensors, ONE HBM/L3 latency ----
    stage_tensor(pred, s, blk_base, lim4, lim1, tid);
    stage_tensor(gt, s + SLICE_DW, blk_base, lim4, lim1, tid);
    __builtin_amdgcn_s_waitcnt(0x0F70);  // vmcnt(0): all DMA stores visible
    __builtin_amdgcn_sched_barrier(0);

    const float* sp = s + tid * NE;             // this lane's pred item
    const float* sg = s + SLICE_DW + tid * NE;  // this lane's gt item

    // ---- pass 1: moments (streamed from LDS, nothing kept) ----
    float Sp0 = 0.f, Sp1 = 0.f, Sp2 = 0.f;
    float Sg0 = 0.f, Sg1 = 0.f, Sg2 = 0.f;
    float pp = 0.f;
    float M[3][3] = {{0.f, 0.f, 0.f}, {0.f, 0.f, 0.f}, {0.f, 0.f, 0.f}};
#pragma unroll
    for (int j = 0; j < NJ; ++j) {
        float px = sp[3 * j + 0], py = sp[3 * j + 1], pz = sp[3 * j + 2];
        float gx = sg[3 * j + 0], gy = sg[3 * j + 1], gz = sg[3 * j + 2];
        Sp0 += px; Sp1 += py; Sp2 += pz;
        Sg0 += gx; Sg1 += gy; Sg2 += gz;
        pp += px * px + py * py + pz * pz;
        M[0][0] += px * gx; M[0][1] += px * gy; M[0][2] += px * gz;
        M[1][0] += py * gx; M[1][1] += py * gy; M[1][2] += py * gz;
        M[2][0] += pz * gx; M[2][1] += pz * gy; M[2][2] += pz * gz;
    }
    // Anti-spill fence (round-2 lesson): pass-1 LDS reads die here; pass 2
    // re-streams from LDS instead of keeping 84 floats live across Jacobi.
    __asm__ __volatile__("" ::: "memory");

    const float invJ = 1.0f / (float)NJ;
    float mp[3] = {Sp0 * invJ, Sp1 * invJ, Sp2 * invJ};
    float mg[3] = {Sg0 * invJ, Sg1 * invJ, Sg2 * invJ};

    float K[3][3];
#pragma unroll
    for (int i = 0; i < 3; ++i)
#pragma unroll
        for (int j = 0; j < 3; ++j)
            K[i][j] = M[i][j] - (float)NJ * mp[i] * mg[j];
    float var1 = pp - (float)NJ * (mp[0] * mp[0] + mp[1] * mp[1] + mp[2] * mp[2]);
    var1 = fmaxf(var1, 1e-30f);

    // ---- A = K^T K, Jacobi (5 sweeps, branchless) ----
    float A[3][3];
#pragma unroll
    for (int i = 0; i < 3; ++i)
#pragma unroll
        for (int j = 0; j < 3; ++j)
            A[i][j] = K[0][i] * K[0][j] + K[1][i] * K[1][j] + K[2][i] * K[2][j];
    float V[3][3] = {{1.f, 0.f, 0.f}, {0.f, 1.f, 0.f}, {0.f, 0.f, 1.f}};
#pragma unroll
    for (int sweep = 0; sweep < 5; ++sweep) {
        jrot<0, 1, 2>(A, V);
        jrot<0, 2, 1>(A, V);
        jrot<1, 2, 0>(A, V);
    }
    float lam0 = A[0][0], lam1 = A[1][1], lam2 = A[2][2];

#define SWAPCOL(la, lb, a, b)                                     \
    {                                                             \
        float _t;                                                 \
        _t = la; la = lb; lb = _t;                                \
        _t = V[0][a]; V[0][a] = V[0][b]; V[0][b] = _t;            \
        _t = V[1][a]; V[1][a] = V[1][b]; V[1][b] = _t;            \
        _t = V[2][a]; V[2][a] = V[2][b]; V[2][b] = _t;            \
    }
    if (lam0 < lam1) SWAPCOL(lam0, lam1, 0, 1)
    if (lam0 < lam2) SWAPCOL(lam0, lam2, 0, 2)
    if (lam1 < lam2) SWAPCOL(lam1, lam2, 1, 2)
#undef SWAPCOL

    float v0[3] = {V[0][0], V[1][0], V[2][0]};
    float v1[3] = {V[0][1], V[1][1], V[2][1]};
    float v2[3] = {V[0][2], V[1][2], V[2][2]};

    // det(V) = +1
    float cxx = v0[1] * v1[2] - v0[2] * v1[1];
    float cxy = v0[2] * v1[0] - v0[0] * v1[2];
    float cxz = v0[0] * v1[1] - v0[1] * v1[0];
    float detv = cxx * v2[0] + cxy * v2[1] + cxz * v2[2];
    if (detv < 0.f) { v2[0] = -v2[0]; v2[1] = -v2[1]; v2[2] = -v2[2]; }

    // U via K*v + Gram-Schmidt; u3 = u1 x u2 -> det(U)=+1
    float w0[3], w1[3];
#pragma unroll
    for (int i = 0; i < 3; ++i) {
        w0[i] = K[i][0] * v0[0] + K[i][1] * v0[1] + K[i][2] * v0[2];
        w1[i] = K[i][0] * v1[0] + K[i][1] * v1[1] + K[i][2] * v1[2];
    }
    float inv0 = frsq(fmaxf(w0[0] * w0[0] + w0[1] * w0[1] + w0[2] * w0[2], 1e-30f));
    float u1[3] = {w0[0] * inv0, w0[1] * inv0, w0[2] * inv0};
    float d1 = u1[0] * w1[0] + u1[1] * w1[1] + u1[2] * w1[2];
    w1[0] -= d1 * u1[0]; w1[1] -= d1 * u1[1]; w1[2] -= d1 * u1[2];
    float inv1 = frsq(fmaxf(w1[0] * w1[0] + w1[1] * w1[1] + w1[2] * w1[2], 1e-30f));
    float u2[3] = {w1[0] * inv1, w1[1] * inv1, w1[2] * inv1};
    float u3[3] = {u1[1] * u2[2] - u1[2] * u2[1],
                   u1[2] * u2[0] - u1[0] * u2[2],
                   u1[0] * u2[1] - u1[1] * u2[0]};

    // R = V U^T
    float R[3][3];
#pragma unroll
    for (int i = 0; i < 3; ++i) {
        R[i][0] = v0[i] * u1[0] + v1[i] * u2[0] + v2[i] * u3[0];
        R[i][1] = v0[i] * u1[1] + v1[i] * u2[1] + v2[i] * u3[1];
        R[i][2] = v0[i] * u1[2] + v1[i] * u2[2] + v2[i] * u3[2];
    }
    float trRK = 0.f;
#pragma unroll
    for (int i = 0; i < 3; ++i)
#pragma unroll
        for (int j = 0; j < 3; ++j)
            trRK += R[i][j] * K[j][i];
    float scale = trRK * frcp(var1);

    // ---- pass 2: loss (both tensors re-streamed from LDS) ----
    float acc = 0.f;
#pragma unroll
    for (int j = 0; j < NJ; ++j) {
        float x0 = sp[3 * j + 0] - mp[0];
        float x1 = sp[3 * j + 1] - mp[1];
        float x2 = sp[3 * j + 2] - mp[2];
        float y0 = sg[3 * j + 0] - mg[0];
        float y1 = sg[3 * j + 1] - mg[1];
        float y2 = sg[3 * j + 2] - mg[2];
        float e0 = scale * (R[0][0] * x0 + R[0][1] * x1 + R[0][2] * x2) - y0;
        float e1 = scale * (R[1][0] * x0 + R[1][1] * x1 + R[1][2] * x2) - y1;
        float e2 = scale * (R[2][0] * x0 + R[2][1] * x1 + R[2][2] * x2) - y2;
        acc += fsqr(e0 * e0 + e1 * e1 + e2 * e2);
    }
    if (me < n_items) out[me] = acc * invJ;
}

extern "C" void kernel_launch(void* const* d_in, const int* in_sizes, int n_in,
                              void* d_out, int out_size, void* d_ws, size_t ws_size,
                              hipStream_t stream) {
    const float* pred = (const float*)d_in[0];
    const float* gt = (const float*)d_in[1];
    float* out = (float*)d_out;
    int n_items = in_sizes[0] / NE;  // 262144
    int grid = (n_items + TPB - 1) / TPB;  // 4096
    pampjpe_kernel<<<grid, TPB, 0, stream>>>(pred, gt, out, n_items);
}